// Round 20
// baseline (147.219 us; speedup 1.0000x reference)
//
#include <hip/hip_runtime.h>

// Batched Kalman step: G groups, S=16, M=8, fp32 math (H,F stored f16 in regs).
// R20: get natural VGPR <= 128 (the 4-waves/SIMD bucket, m69) by PHASE
// live-set surgery -- attributes are radioactive (R4/R9/R17 spills):
//  - IN-PLACE Gauss-Jordan inversion (no augmented identity): -16 VGPR at
//    the peak phase. S -> S^-1 with per-component owner fixups:
//      p=S[k][k]; scale row k by 1/p; S[k][k]=1/p;
//      for i!=k: f=S[i][k]; row_i -= f*row_k; S[i][k] = -f/p.
//  - resd computed up front; mean reloaded later (not held across GJ)
//  - R rows loaded inside S-compute; HT f16 (R18-validated numerics)
//  - FT (f16) loaded AFTER stream-X behind sched_barrier(0) -> stream-X
//    live ~114; epilogue live ~112+ring8. 2-deep Q ring.
// At 4 waves/SIMD the exposed F/Q latencies are covered by TLP (the 2-wave
// regime could not cover them: R13).

typedef float v2f __attribute__((ext_vector_type(2)));
typedef _Float16 h2 __attribute__((ext_vector_type(2)));

__device__ __forceinline__ float bq(float x, int t) {
    switch (t & 3) {
    case 0:  return __int_as_float(__builtin_amdgcn_mov_dpp(__float_as_int(x), 0x00, 0xF, 0xF, true));
    case 1:  return __int_as_float(__builtin_amdgcn_mov_dpp(__float_as_int(x), 0x55, 0xF, 0xF, true));
    case 2:  return __int_as_float(__builtin_amdgcn_mov_dpp(__float_as_int(x), 0xAA, 0xF, 0xF, true));
    default: return __int_as_float(__builtin_amdgcn_mov_dpp(__float_as_int(x), 0xFF, 0xF, 0xF, true));
    }
}
__device__ __forceinline__ v2f splat(float c) { v2f r; r.x = c; r.y = c; return r; }
__device__ __forceinline__ v2f up2(h2 h) { v2f r; r.x = (float)h.x; r.y = (float)h.y; return r; }

__global__ __launch_bounds__(64) void kalman_kernel(
    const float* __restrict__ g_in,
    const float* __restrict__ g_mean,
    const float* __restrict__ g_cov,
    const float* __restrict__ g_H,
    const float* __restrict__ g_R,
    const float* __restrict__ g_F,
    const float* __restrict__ g_Q,
    float* __restrict__ g_out,
    int G)
{
    const int l = threadIdx.x & 3;                         // lane in quad
    const int g = (blockIdx.x << 4) | (threadIdx.x >> 2);  // group id

    const float* const Pp = g_cov + (size_t)g * 256;
    const float* const Hp = g_H   + (size_t)g * 128;
    const float* const Rp = g_R   + (size_t)g * 64;
    const float* const Fp = g_F   + (size_t)g * 256;
    const float* const Qp = g_Q   + (size_t)g * 256;

    // ---- P col-slab (cols 4l..4l+3) ----
    v2f Plo[16], Phi[16];
    #pragma unroll
    for (int k = 0; k < 16; ++k) {
        const float4 t = *reinterpret_cast<const float4*>(Pp + k*16 + 4*l);
        Plo[k].x=t.x; Plo[k].y=t.y; Phi[k].x=t.z; Phi[k].y=t.w;
    }
    // ---- HT16[k] = {H[2l][k], H[2l+1][k]} packed f16 (16 VGPR) ----
    h2 HT16[16];
    {
        float4 ra[4], rb[4];
        #pragma unroll
        for (int p = 0; p < 4; ++p) {
            ra[p] = *reinterpret_cast<const float4*>(Hp + (2*l  )*16 + 4*p);
            rb[p] = *reinterpret_cast<const float4*>(Hp + (2*l+1)*16 + 4*p);
        }
        #pragma unroll
        for (int p = 0; p < 4; ++p) {
            HT16[4*p+0].x=(_Float16)ra[p].x; HT16[4*p+0].y=(_Float16)rb[p].x;
            HT16[4*p+1].x=(_Float16)ra[p].y; HT16[4*p+1].y=(_Float16)rb[p].y;
            HT16[4*p+2].x=(_Float16)ra[p].z; HT16[4*p+2].y=(_Float16)rb[p].z;
            HT16[4*p+3].x=(_Float16)ra[p].w; HT16[4*p+3].y=(_Float16)rb[p].w;
        }
    }
    // ---- resd = in - H@mean (mean transient: NOT held across GJ) ----
    v2f resd;
    {
        const float2 it = *reinterpret_cast<const float2*>(g_in + (size_t)g*8 + 2*l);
        const float4 mt = *reinterpret_cast<const float4*>(g_mean + (size_t)g*16 + 4*l);
        resd.x = it.x; resd.y = it.y;
        #pragma unroll
        for (int k = 0; k < 16; ++k) {
            const float m = bq((k&2) ? ((k&1)?mt.w:mt.z) : ((k&1)?mt.y:mt.x), k>>2);
            resd -= splat(m) * up2(HT16[k]);
        }
    }

    // ---- CT = H@P (col-slab; H[i][k] via f16 comp + DPP) ----
    v2f CTlo[8], CThi[8];
    #pragma unroll
    for (int i = 0; i < 8; ++i) {
        v2f alo = {0.f,0.f}, ahi = {0.f,0.f};
        #pragma unroll
        for (int k = 0; k < 16; ++k) {
            const float h = bq((float)((i&1) ? HT16[k].y : HT16[k].x), i>>1);
            alo += splat(h) * Plo[k];
            ahi += splat(h) * Phi[k];
        }
        CTlo[i]=alo; CThi[i]=ahi;
    }

    // ---- S = CT@H^T + R (R rows loaded in-loop; HT dies here) ----
    v2f S[8];
    #pragma unroll
    for (int i = 0; i < 8; ++i) {
        const float2 rt = *reinterpret_cast<const float2*>(Rp + i*8 + 2*l);
        v2f acc; acc.x = rt.x; acc.y = rt.y;
        #pragma unroll
        for (int k = 0; k < 16; ++k) {
            const float c = bq((k&2) ? ((k&1)?CThi[i].y:CThi[i].x)
                                     : ((k&1)?CTlo[i].y:CTlo[i].x), k>>2);
            acc += splat(c) * up2(HT16[k]);
        }
        S[i] = acc;
    }

    // ---- IN-PLACE Gauss-Jordan: S -> S^-1 (SPD, no pivot, no identity) ----
    #pragma unroll
    for (int k = 0; k < 8; ++k) {
        const float p    = bq((k&1) ? S[k].y : S[k].x, k>>1);
        const float pinv = __builtin_amdgcn_rcpf(p);
        S[k] *= splat(pinv);
        S[k].x = (2*l   == k) ? pinv : S[k].x;       // S[k][k] = 1/p
        S[k].y = (2*l+1 == k) ? pinv : S[k].y;
        #pragma unroll
        for (int i = 0; i < 8; ++i) {
            if (i == k) continue;
            const float f  = bq((k&1) ? S[i].y : S[i].x, k>>1);
            const float nf = -f * pinv;
            S[i] -= splat(f) * S[k];
            S[i].x = (2*l   == k) ? nf : S[i].x;     // S[i][k] = -f/p
            S[i].y = (2*l+1 == k) ? nf : S[i].y;
        }
    }
    // S now holds Sinv.

    // ---- stream-X: nm += X[m]*resd ; NC(P) -= CT^T[.,m] (x) X[m] ----
    v2f nmL, nmH;
    {
        const float4 mt = *reinterpret_cast<const float4*>(g_mean + (size_t)g*16 + 4*l);
        nmL.x=mt.x; nmL.y=mt.y; nmH.x=mt.z; nmH.y=mt.w;
    }
    #pragma unroll
    for (int m = 0; m < 8; ++m) {
        v2f xlo = {0.f,0.f}, xhi = {0.f,0.f};
        #pragma unroll
        for (int j = 0; j < 8; ++j) {
            const float s = bq((j&1) ? S[m].y : S[m].x, j>>1);
            xlo += splat(s) * CTlo[j];
            xhi += splat(s) * CThi[j];
        }
        const float r = bq((m&1) ? resd.y : resd.x, m>>1);
        nmL += splat(r) * xlo;
        nmH += splat(r) * xhi;
        #pragma unroll
        for (int s2 = 0; s2 < 16; ++s2) {
            const float c = bq((s2&2) ? ((s2&1)?CThi[m].y:CThi[m].x)
                                      : ((s2&1)?CTlo[m].y:CTlo[m].x), s2>>2);
            Plo[s2] -= splat(c) * xlo;
            Phi[s2] -= splat(c) * xhi;
        }
    }
    // P holds NC. CT/S/resd dead past here.
    __builtin_amdgcn_sched_barrier(0);   // fence: F/Q must NOT hoist above

    // ---- FT (f16 pack, 32 VGPR): FT16a[t]={F[4l][t],F[4l+1][t]}, b = rows 2,3 ----
    h2 FT16a[16], FT16b[16];
    {
        #pragma unroll
        for (int p = 0; p < 4; ++p) {
            const float4 r0 = *reinterpret_cast<const float4*>(Fp + (4*l+0)*16 + 4*p);
            const float4 r1 = *reinterpret_cast<const float4*>(Fp + (4*l+1)*16 + 4*p);
            const float4 r2 = *reinterpret_cast<const float4*>(Fp + (4*l+2)*16 + 4*p);
            const float4 r3 = *reinterpret_cast<const float4*>(Fp + (4*l+3)*16 + 4*p);
            FT16a[4*p+0].x=(_Float16)r0.x; FT16a[4*p+0].y=(_Float16)r1.x;
            FT16b[4*p+0].x=(_Float16)r2.x; FT16b[4*p+0].y=(_Float16)r3.x;
            FT16a[4*p+1].x=(_Float16)r0.y; FT16a[4*p+1].y=(_Float16)r1.y;
            FT16b[4*p+1].x=(_Float16)r2.y; FT16b[4*p+1].y=(_Float16)r3.y;
            FT16a[4*p+2].x=(_Float16)r0.z; FT16a[4*p+2].y=(_Float16)r1.z;
            FT16b[4*p+2].x=(_Float16)r2.z; FT16b[4*p+2].y=(_Float16)r3.z;
            FT16a[4*p+3].x=(_Float16)r0.w; FT16a[4*p+3].y=(_Float16)r1.w;
            FT16b[4*p+3].x=(_Float16)r2.w; FT16b[4*p+3].y=(_Float16)r3.w;
        }
    }

    // ---- pred_mean = F @ nm -> coalesced float4 ----
    {
        v2f plo = {0.f,0.f}, phi = {0.f,0.f};
        #pragma unroll
        for (int k = 0; k < 16; ++k) {
            const float m = bq((k&2) ? ((k&1)?nmH.y:nmH.x)
                                     : ((k&1)?nmL.y:nmL.x), k>>2);
            plo += splat(m) * up2(FT16a[k]);
            phi += splat(m) * up2(FT16b[k]);
        }
        *reinterpret_cast<float4*>(g_out + (size_t)g*16 + 4*l) =
            make_float4(plo.x, plo.y, phi.x, phi.y);
    }

    // ---- pred_cov rows, fused W=F@NC then out=W@F^T+Q (2-deep Q ring) ----
    float* const out_pc = g_out + (size_t)G*16 + (size_t)g*256;
    float4 qbuf[2];
    #pragma unroll
    for (int i = 0; i < 2; ++i)
        qbuf[i] = *reinterpret_cast<const float4*>(Qp + i*16 + 4*l);
    #pragma unroll
    for (int i = 0; i < 16; ++i) {
        v2f wlo = {0.f,0.f}, whi = {0.f,0.f};
        #pragma unroll
        for (int k = 0; k < 16; ++k) {
            const float f = bq((float)((i&2) ? ((i&1)?FT16b[k].y:FT16b[k].x)
                                             : ((i&1)?FT16a[k].y:FT16a[k].x)), i>>2);
            wlo += splat(f) * Plo[k];
            whi += splat(f) * Phi[k];
        }
        const float4 qv = qbuf[i & 1];
        if (i + 2 < 16)
            qbuf[i & 1] = *reinterpret_cast<const float4*>(Qp + (i+2)*16 + 4*l);
        v2f olo; olo.x=qv.x; olo.y=qv.y;
        v2f ohi; ohi.x=qv.z; ohi.y=qv.w;
        #pragma unroll
        for (int t = 0; t < 16; ++t) {
            const float wb = bq((t&2) ? ((t&1)?whi.y:whi.x)
                                      : ((t&1)?wlo.y:wlo.x), t>>2);
            olo += splat(wb) * up2(FT16a[t]);
            ohi += splat(wb) * up2(FT16b[t]);
        }
        *reinterpret_cast<float4*>(out_pc + i*16 + 4*l) =
            make_float4(olo.x, olo.y, ohi.x, ohi.y);
    }
}

extern "C" void kernel_launch(void* const* d_in, const int* in_sizes, int n_in,
                              void* d_out, int out_size, void* d_ws, size_t ws_size,
                              hipStream_t stream) {
    const float* g_in   = (const float*)d_in[0];
    const float* g_mean = (const float*)d_in[1];
    const float* g_cov  = (const float*)d_in[2];
    const float* g_H    = (const float*)d_in[3];
    const float* g_R    = (const float*)d_in[4];
    const float* g_F    = (const float*)d_in[5];
    const float* g_Q    = (const float*)d_in[6];
    float* out = (float*)d_out;
    const int G = in_sizes[2] / 256;     // cov is [G,16,16]
    kalman_kernel<<<G/16, 64, 0, stream>>>(g_in, g_mean, g_cov, g_H, g_R, g_F, g_Q, out, G);
}

// Round 21
// 144.649 us; speedup vs baseline: 1.0178x; 1.0178x over previous
//
#include <hip/hip_runtime.h>

// Batched Kalman step: G groups, S=16, M=8, fp32 math (P-base & F stored f16).
// R21: the 132-VGPR floor (identical across R11/R13/R18/R20) is the FRONT
// in-flight batch: P(64)+H(32)+R(16)+misc held simultaneously. Fix:
//  - P STREAMED through CT in 4-row chunks (16 regs in flight, consumed
//    k-wise, discarded) -- never held in f32
//  - P retained only as packed f16 (32 regs) to seed NC (error into
//    pred_cov < 3e-4; FT-f16 already validated at absmax 0.0156)
//  - H stays f32 (no cvt tax in hot CT/S loops); in-place GJ (R20);
//    FT f16 after fence; 4-deep Q ring
// Phase peaks all ~114-118 -> natural VGPR <= 128 -> 4 waves/SIMD, which
// also covers the post-fence F/Q latency that sank R20 at 2 waves.
// NO launch_bounds min-waves (R4/R9/R17: over-clamp -> GB spills).

typedef float v2f __attribute__((ext_vector_type(2)));
typedef _Float16 h2 __attribute__((ext_vector_type(2)));

__device__ __forceinline__ float bq(float x, int t) {
    switch (t & 3) {
    case 0:  return __int_as_float(__builtin_amdgcn_mov_dpp(__float_as_int(x), 0x00, 0xF, 0xF, true));
    case 1:  return __int_as_float(__builtin_amdgcn_mov_dpp(__float_as_int(x), 0x55, 0xF, 0xF, true));
    case 2:  return __int_as_float(__builtin_amdgcn_mov_dpp(__float_as_int(x), 0xAA, 0xF, 0xF, true));
    default: return __int_as_float(__builtin_amdgcn_mov_dpp(__float_as_int(x), 0xFF, 0xF, 0xF, true));
    }
}
__device__ __forceinline__ v2f splat(float c) { v2f r; r.x = c; r.y = c; return r; }
__device__ __forceinline__ v2f up2(h2 h) { v2f r; r.x = (float)h.x; r.y = (float)h.y; return r; }
__device__ __forceinline__ h2 pk2(v2f v) { h2 r; r.x = (_Float16)v.x; r.y = (_Float16)v.y; return r; }

__global__ __launch_bounds__(256) void kalman_kernel(
    const float* __restrict__ g_in,
    const float* __restrict__ g_mean,
    const float* __restrict__ g_cov,
    const float* __restrict__ g_H,
    const float* __restrict__ g_R,
    const float* __restrict__ g_F,
    const float* __restrict__ g_Q,
    float* __restrict__ g_out,
    int G)
{
    const int l = threadIdx.x & 3;                         // lane in quad
    const int g = (blockIdx.x << 6) | (threadIdx.x >> 2);  // group id

    const float* const Pp = g_cov + (size_t)g * 256;
    const float* const Hp = g_H   + (size_t)g * 128;
    const float* const Rp = g_R   + (size_t)g * 64;
    const float* const Fp = g_F   + (size_t)g * 256;
    const float* const Qp = g_Q   + (size_t)g * 256;

    // ---- HT[k] = {H[2l][k], H[2l+1][k]} f32 (32 VGPR) ----
    v2f HT[16];
    {
        float4 ra[4], rb[4];
        #pragma unroll
        for (int p = 0; p < 4; ++p) {
            ra[p] = *reinterpret_cast<const float4*>(Hp + (2*l  )*16 + 4*p);
            rb[p] = *reinterpret_cast<const float4*>(Hp + (2*l+1)*16 + 4*p);
        }
        #pragma unroll
        for (int p = 0; p < 4; ++p) {
            HT[4*p+0].x=ra[p].x; HT[4*p+0].y=rb[p].x;
            HT[4*p+1].x=ra[p].y; HT[4*p+1].y=rb[p].y;
            HT[4*p+2].x=ra[p].z; HT[4*p+2].y=rb[p].z;
            HT[4*p+3].x=ra[p].w; HT[4*p+3].y=rb[p].w;
        }
    }
    // ---- resd = in - H@mean (mean transient) ----
    v2f resd;
    {
        const float2 it = *reinterpret_cast<const float2*>(g_in + (size_t)g*8 + 2*l);
        const float4 mt = *reinterpret_cast<const float4*>(g_mean + (size_t)g*16 + 4*l);
        resd.x = it.x; resd.y = it.y;
        #pragma unroll
        for (int k = 0; k < 16; ++k) {
            const float m = bq((k&2) ? ((k&1)?mt.w:mt.z) : ((k&1)?mt.y:mt.x), k>>2);
            resd -= splat(m) * HT[k];
        }
    }

    // ---- CT = H@P with P STREAMED in 4-row chunks; P kept only as f16 ----
    v2f CTlo[8], CThi[8];
    #pragma unroll
    for (int i = 0; i < 8; ++i) { CTlo[i] = splat(0.f); CThi[i] = splat(0.f); }
    h2 PF16a[16], PF16b[16];                  // P[k][4l..4l+3] packed (32 VGPR)
    #pragma unroll
    for (int p = 0; p < 4; ++p) {
        float4 c[4];
        #pragma unroll
        for (int r = 0; r < 4; ++r)
            c[r] = *reinterpret_cast<const float4*>(Pp + (4*p+r)*16 + 4*l);
        #pragma unroll
        for (int r = 0; r < 4; ++r) {
            const int k = 4*p + r;
            v2f plo, phi;
            plo.x=c[r].x; plo.y=c[r].y; phi.x=c[r].z; phi.y=c[r].w;
            #pragma unroll
            for (int i = 0; i < 8; ++i) {
                const float h = bq((i&1) ? HT[k].y : HT[k].x, i>>1);
                CTlo[i] += splat(h) * plo;
                CThi[i] += splat(h) * phi;
            }
            PF16a[k] = pk2(plo);
            PF16b[k] = pk2(phi);
        }
    }

    // ---- S = CT@H^T + R (R rows loaded in-loop; HT dies here) ----
    v2f S[8];
    #pragma unroll
    for (int i = 0; i < 8; ++i) {
        const float2 rt = *reinterpret_cast<const float2*>(Rp + i*8 + 2*l);
        v2f acc; acc.x = rt.x; acc.y = rt.y;
        #pragma unroll
        for (int k = 0; k < 16; ++k) {
            const float c = bq((k&2) ? ((k&1)?CThi[i].y:CThi[i].x)
                                     : ((k&1)?CTlo[i].y:CTlo[i].x), k>>2);
            acc += splat(c) * HT[k];
        }
        S[i] = acc;
    }

    // ---- IN-PLACE Gauss-Jordan: S -> S^-1 (R20-verified) ----
    #pragma unroll
    for (int k = 0; k < 8; ++k) {
        const float p    = bq((k&1) ? S[k].y : S[k].x, k>>1);
        const float pinv = __builtin_amdgcn_rcpf(p);
        S[k] *= splat(pinv);
        S[k].x = (2*l   == k) ? pinv : S[k].x;
        S[k].y = (2*l+1 == k) ? pinv : S[k].y;
        #pragma unroll
        for (int i = 0; i < 8; ++i) {
            if (i == k) continue;
            const float f  = bq((k&1) ? S[i].y : S[i].x, k>>1);
            const float nf = -f * pinv;
            S[i] -= splat(f) * S[k];
            S[i].x = (2*l   == k) ? nf : S[i].x;
            S[i].y = (2*l+1 == k) ? nf : S[i].y;
        }
    }
    // S = Sinv.

    // ---- NC seeded from f16 P (PF16 dies row-by-row) ----
    v2f NClo[16], NChi[16];
    #pragma unroll
    for (int k = 0; k < 16; ++k) {
        NClo[k] = up2(PF16a[k]);
        NChi[k] = up2(PF16b[k]);
    }
    // ---- stream-X: nm += X[m]*resd ; NC -= CT^T[.,m] (x) X[m] ----
    v2f nmL, nmH;
    {
        const float4 mt = *reinterpret_cast<const float4*>(g_mean + (size_t)g*16 + 4*l);
        nmL.x=mt.x; nmL.y=mt.y; nmH.x=mt.z; nmH.y=mt.w;
    }
    #pragma unroll
    for (int m = 0; m < 8; ++m) {
        v2f xlo = {0.f,0.f}, xhi = {0.f,0.f};
        #pragma unroll
        for (int j = 0; j < 8; ++j) {
            const float s = bq((j&1) ? S[m].y : S[m].x, j>>1);
            xlo += splat(s) * CTlo[j];
            xhi += splat(s) * CThi[j];
        }
        const float r = bq((m&1) ? resd.y : resd.x, m>>1);
        nmL += splat(r) * xlo;
        nmH += splat(r) * xhi;
        #pragma unroll
        for (int s2 = 0; s2 < 16; ++s2) {
            const float c = bq((s2&2) ? ((s2&1)?CThi[m].y:CThi[m].x)
                                      : ((s2&1)?CTlo[m].y:CTlo[m].x), s2>>2);
            NClo[s2] -= splat(c) * xlo;
            NChi[s2] -= splat(c) * xhi;
        }
    }
    // NC done. CT/S/resd dead past here.
    __builtin_amdgcn_sched_barrier(0);   // fence: F/Q must not hoist above

    // ---- FT (f16 pack, 32 VGPR) ----
    h2 FT16a[16], FT16b[16];
    {
        #pragma unroll
        for (int p = 0; p < 4; ++p) {
            const float4 r0 = *reinterpret_cast<const float4*>(Fp + (4*l+0)*16 + 4*p);
            const float4 r1 = *reinterpret_cast<const float4*>(Fp + (4*l+1)*16 + 4*p);
            const float4 r2 = *reinterpret_cast<const float4*>(Fp + (4*l+2)*16 + 4*p);
            const float4 r3 = *reinterpret_cast<const float4*>(Fp + (4*l+3)*16 + 4*p);
            FT16a[4*p+0].x=(_Float16)r0.x; FT16a[4*p+0].y=(_Float16)r1.x;
            FT16b[4*p+0].x=(_Float16)r2.x; FT16b[4*p+0].y=(_Float16)r3.x;
            FT16a[4*p+1].x=(_Float16)r0.y; FT16a[4*p+1].y=(_Float16)r1.y;
            FT16b[4*p+1].x=(_Float16)r2.y; FT16b[4*p+1].y=(_Float16)r3.y;
            FT16a[4*p+2].x=(_Float16)r0.z; FT16a[4*p+2].y=(_Float16)r1.z;
            FT16b[4*p+2].x=(_Float16)r2.z; FT16b[4*p+2].y=(_Float16)r3.z;
            FT16a[4*p+3].x=(_Float16)r0.w; FT16a[4*p+3].y=(_Float16)r1.w;
            FT16b[4*p+3].x=(_Float16)r2.w; FT16b[4*p+3].y=(_Float16)r3.w;
        }
    }

    // ---- pred_mean = F @ nm -> coalesced float4 ----
    {
        v2f plo = {0.f,0.f}, phi = {0.f,0.f};
        #pragma unroll
        for (int k = 0; k < 16; ++k) {
            const float m = bq((k&2) ? ((k&1)?nmH.y:nmH.x)
                                     : ((k&1)?nmL.y:nmL.x), k>>2);
            plo += splat(m) * up2(FT16a[k]);
            phi += splat(m) * up2(FT16b[k]);
        }
        *reinterpret_cast<float4*>(g_out + (size_t)g*16 + 4*l) =
            make_float4(plo.x, plo.y, phi.x, phi.y);
    }

    // ---- pred_cov rows, fused W=F@NC then out=W@F^T+Q (4-deep Q ring) ----
    float* const out_pc = g_out + (size_t)G*16 + (size_t)g*256;
    float4 qbuf[4];
    #pragma unroll
    for (int i = 0; i < 4; ++i)
        qbuf[i] = *reinterpret_cast<const float4*>(Qp + i*16 + 4*l);
    #pragma unroll
    for (int i = 0; i < 16; ++i) {
        v2f wlo = {0.f,0.f}, whi = {0.f,0.f};
        #pragma unroll
        for (int k = 0; k < 16; ++k) {
            const float f = bq((float)((i&2) ? ((i&1)?FT16b[k].y:FT16b[k].x)
                                             : ((i&1)?FT16a[k].y:FT16a[k].x)), i>>2);
            wlo += splat(f) * NClo[k];
            whi += splat(f) * NChi[k];
        }
        const float4 qv = qbuf[i & 3];
        if (i + 4 < 16)
            qbuf[i & 3] = *reinterpret_cast<const float4*>(Qp + (i+4)*16 + 4*l);
        v2f olo; olo.x=qv.x; olo.y=qv.y;
        v2f ohi; ohi.x=qv.z; ohi.y=qv.w;
        #pragma unroll
        for (int t = 0; t < 16; ++t) {
            const float wb = bq((t&2) ? ((t&1)?whi.y:whi.x)
                                      : ((t&1)?wlo.y:wlo.x), t>>2);
            olo += splat(wb) * up2(FT16a[t]);
            ohi += splat(wb) * up2(FT16b[t]);
        }
        *reinterpret_cast<float4*>(out_pc + i*16 + 4*l) =
            make_float4(olo.x, olo.y, ohi.x, ohi.y);
    }
}

extern "C" void kernel_launch(void* const* d_in, const int* in_sizes, int n_in,
                              void* d_out, int out_size, void* d_ws, size_t ws_size,
                              hipStream_t stream) {
    const float* g_in   = (const float*)d_in[0];
    const float* g_mean = (const float*)d_in[1];
    const float* g_cov  = (const float*)d_in[2];
    const float* g_H    = (const float*)d_in[3];
    const float* g_R    = (const float*)d_in[4];
    const float* g_F    = (const float*)d_in[5];
    const float* g_Q    = (const float*)d_in[6];
    float* out = (float*)d_out;
    const int G = in_sizes[2] / 256;     // cov is [G,16,16]
    kalman_kernel<<<G/64, 256, 0, stream>>>(g_in, g_mean, g_cov, g_H, g_R, g_F, g_Q, out, G);
}

// Round 22
// 139.285 us; speedup vs baseline: 1.0570x; 1.0385x over previous
//
#include <hip/hip_runtime.h>

// Batched Kalman step: G groups, S=16, M=8, fp32 math (P-base & F stored f16).
// R22 = R21 + __attribute__((amdgpu_num_vgpr(128))).
//   Natural allocation is 132 VGPR for EVERY structure tried (R11/R13/R18/
//   R20/R21) -- the last ~4 regs are allocator slack. 132 -> 2 waves/SIMD;
//   128 -> 4 waves/SIMD (bucket halving at 64/128/256, confirmed by R17's
//   VGPR=64 -> 46% occ = 4x the 10.6% at 132).
//   amdgpu_num_vgpr sets an EXACT cap (unlike the min-waves clause, which
//   let the compiler pick 32/84/64 in R4/R9/R17 -> GB spills). A 4-reg
//   squeeze should be absorbed by rescheduling; tripwire = WRITE_SIZE.

typedef float v2f __attribute__((ext_vector_type(2)));
typedef _Float16 h2 __attribute__((ext_vector_type(2)));

__device__ __forceinline__ float bq(float x, int t) {
    switch (t & 3) {
    case 0:  return __int_as_float(__builtin_amdgcn_mov_dpp(__float_as_int(x), 0x00, 0xF, 0xF, true));
    case 1:  return __int_as_float(__builtin_amdgcn_mov_dpp(__float_as_int(x), 0x55, 0xF, 0xF, true));
    case 2:  return __int_as_float(__builtin_amdgcn_mov_dpp(__float_as_int(x), 0xAA, 0xF, 0xF, true));
    default: return __int_as_float(__builtin_amdgcn_mov_dpp(__float_as_int(x), 0xFF, 0xF, 0xF, true));
    }
}
__device__ __forceinline__ v2f splat(float c) { v2f r; r.x = c; r.y = c; return r; }
__device__ __forceinline__ v2f up2(h2 h) { v2f r; r.x = (float)h.x; r.y = (float)h.y; return r; }
__device__ __forceinline__ h2 pk2(v2f v) { h2 r; r.x = (_Float16)v.x; r.y = (_Float16)v.y; return r; }

__global__ __launch_bounds__(256)
__attribute__((amdgpu_num_vgpr(128)))
void kalman_kernel(
    const float* __restrict__ g_in,
    const float* __restrict__ g_mean,
    const float* __restrict__ g_cov,
    const float* __restrict__ g_H,
    const float* __restrict__ g_R,
    const float* __restrict__ g_F,
    const float* __restrict__ g_Q,
    float* __restrict__ g_out,
    int G)
{
    const int l = threadIdx.x & 3;                         // lane in quad
    const int g = (blockIdx.x << 6) | (threadIdx.x >> 2);  // group id

    const float* const Pp = g_cov + (size_t)g * 256;
    const float* const Hp = g_H   + (size_t)g * 128;
    const float* const Rp = g_R   + (size_t)g * 64;
    const float* const Fp = g_F   + (size_t)g * 256;
    const float* const Qp = g_Q   + (size_t)g * 256;

    // ---- HT[k] = {H[2l][k], H[2l+1][k]} f32 (32 VGPR) ----
    v2f HT[16];
    {
        float4 ra[4], rb[4];
        #pragma unroll
        for (int p = 0; p < 4; ++p) {
            ra[p] = *reinterpret_cast<const float4*>(Hp + (2*l  )*16 + 4*p);
            rb[p] = *reinterpret_cast<const float4*>(Hp + (2*l+1)*16 + 4*p);
        }
        #pragma unroll
        for (int p = 0; p < 4; ++p) {
            HT[4*p+0].x=ra[p].x; HT[4*p+0].y=rb[p].x;
            HT[4*p+1].x=ra[p].y; HT[4*p+1].y=rb[p].y;
            HT[4*p+2].x=ra[p].z; HT[4*p+2].y=rb[p].z;
            HT[4*p+3].x=ra[p].w; HT[4*p+3].y=rb[p].w;
        }
    }
    // ---- resd = in - H@mean (mean transient) ----
    v2f resd;
    {
        const float2 it = *reinterpret_cast<const float2*>(g_in + (size_t)g*8 + 2*l);
        const float4 mt = *reinterpret_cast<const float4*>(g_mean + (size_t)g*16 + 4*l);
        resd.x = it.x; resd.y = it.y;
        #pragma unroll
        for (int k = 0; k < 16; ++k) {
            const float m = bq((k&2) ? ((k&1)?mt.w:mt.z) : ((k&1)?mt.y:mt.x), k>>2);
            resd -= splat(m) * HT[k];
        }
    }

    // ---- CT = H@P with P STREAMED in 4-row chunks; P kept only as f16 ----
    v2f CTlo[8], CThi[8];
    #pragma unroll
    for (int i = 0; i < 8; ++i) { CTlo[i] = splat(0.f); CThi[i] = splat(0.f); }
    h2 PF16a[16], PF16b[16];                  // P[k][4l..4l+3] packed (32 VGPR)
    #pragma unroll
    for (int p = 0; p < 4; ++p) {
        float4 c[4];
        #pragma unroll
        for (int r = 0; r < 4; ++r)
            c[r] = *reinterpret_cast<const float4*>(Pp + (4*p+r)*16 + 4*l);
        #pragma unroll
        for (int r = 0; r < 4; ++r) {
            const int k = 4*p + r;
            v2f plo, phi;
            plo.x=c[r].x; plo.y=c[r].y; phi.x=c[r].z; phi.y=c[r].w;
            #pragma unroll
            for (int i = 0; i < 8; ++i) {
                const float h = bq((i&1) ? HT[k].y : HT[k].x, i>>1);
                CTlo[i] += splat(h) * plo;
                CThi[i] += splat(h) * phi;
            }
            PF16a[k] = pk2(plo);
            PF16b[k] = pk2(phi);
        }
    }

    // ---- S = CT@H^T + R (R rows loaded in-loop; HT dies here) ----
    v2f S[8];
    #pragma unroll
    for (int i = 0; i < 8; ++i) {
        const float2 rt = *reinterpret_cast<const float2*>(Rp + i*8 + 2*l);
        v2f acc; acc.x = rt.x; acc.y = rt.y;
        #pragma unroll
        for (int k = 0; k < 16; ++k) {
            const float c = bq((k&2) ? ((k&1)?CThi[i].y:CThi[i].x)
                                     : ((k&1)?CTlo[i].y:CTlo[i].x), k>>2);
            acc += splat(c) * HT[k];
        }
        S[i] = acc;
    }

    // ---- IN-PLACE Gauss-Jordan: S -> S^-1 (R20-verified) ----
    #pragma unroll
    for (int k = 0; k < 8; ++k) {
        const float p    = bq((k&1) ? S[k].y : S[k].x, k>>1);
        const float pinv = __builtin_amdgcn_rcpf(p);
        S[k] *= splat(pinv);
        S[k].x = (2*l   == k) ? pinv : S[k].x;
        S[k].y = (2*l+1 == k) ? pinv : S[k].y;
        #pragma unroll
        for (int i = 0; i < 8; ++i) {
            if (i == k) continue;
            const float f  = bq((k&1) ? S[i].y : S[i].x, k>>1);
            const float nf = -f * pinv;
            S[i] -= splat(f) * S[k];
            S[i].x = (2*l   == k) ? nf : S[i].x;
            S[i].y = (2*l+1 == k) ? nf : S[i].y;
        }
    }
    // S = Sinv.

    // ---- NC seeded from f16 P ----
    v2f NClo[16], NChi[16];
    #pragma unroll
    for (int k = 0; k < 16; ++k) {
        NClo[k] = up2(PF16a[k]);
        NChi[k] = up2(PF16b[k]);
    }
    // ---- stream-X: nm += X[m]*resd ; NC -= CT^T[.,m] (x) X[m] ----
    v2f nmL, nmH;
    {
        const float4 mt = *reinterpret_cast<const float4*>(g_mean + (size_t)g*16 + 4*l);
        nmL.x=mt.x; nmL.y=mt.y; nmH.x=mt.z; nmH.y=mt.w;
    }
    #pragma unroll
    for (int m = 0; m < 8; ++m) {
        v2f xlo = {0.f,0.f}, xhi = {0.f,0.f};
        #pragma unroll
        for (int j = 0; j < 8; ++j) {
            const float s = bq((j&1) ? S[m].y : S[m].x, j>>1);
            xlo += splat(s) * CTlo[j];
            xhi += splat(s) * CThi[j];
        }
        const float r = bq((m&1) ? resd.y : resd.x, m>>1);
        nmL += splat(r) * xlo;
        nmH += splat(r) * xhi;
        #pragma unroll
        for (int s2 = 0; s2 < 16; ++s2) {
            const float c = bq((s2&2) ? ((s2&1)?CThi[m].y:CThi[m].x)
                                      : ((s2&1)?CTlo[m].y:CTlo[m].x), s2>>2);
            NClo[s2] -= splat(c) * xlo;
            NChi[s2] -= splat(c) * xhi;
        }
    }
    // NC done. CT/S/resd dead past here.
    __builtin_amdgcn_sched_barrier(0);   // fence: F/Q must not hoist above

    // ---- FT (f16 pack, 32 VGPR) ----
    h2 FT16a[16], FT16b[16];
    {
        #pragma unroll
        for (int p = 0; p < 4; ++p) {
            const float4 r0 = *reinterpret_cast<const float4*>(Fp + (4*l+0)*16 + 4*p);
            const float4 r1 = *reinterpret_cast<const float4*>(Fp + (4*l+1)*16 + 4*p);
            const float4 r2 = *reinterpret_cast<const float4*>(Fp + (4*l+2)*16 + 4*p);
            const float4 r3 = *reinterpret_cast<const float4*>(Fp + (4*l+3)*16 + 4*p);
            FT16a[4*p+0].x=(_Float16)r0.x; FT16a[4*p+0].y=(_Float16)r1.x;
            FT16b[4*p+0].x=(_Float16)r2.x; FT16b[4*p+0].y=(_Float16)r3.x;
            FT16a[4*p+1].x=(_Float16)r0.y; FT16a[4*p+1].y=(_Float16)r1.y;
            FT16b[4*p+1].x=(_Float16)r2.y; FT16b[4*p+1].y=(_Float16)r3.y;
            FT16a[4*p+2].x=(_Float16)r0.z; FT16a[4*p+2].y=(_Float16)r1.z;
            FT16b[4*p+2].x=(_Float16)r2.z; FT16b[4*p+2].y=(_Float16)r3.z;
            FT16a[4*p+3].x=(_Float16)r0.w; FT16a[4*p+3].y=(_Float16)r1.w;
            FT16b[4*p+3].x=(_Float16)r2.w; FT16b[4*p+3].y=(_Float16)r3.w;
        }
    }

    // ---- pred_mean = F @ nm -> coalesced float4 ----
    {
        v2f plo = {0.f,0.f}, phi = {0.f,0.f};
        #pragma unroll
        for (int k = 0; k < 16; ++k) {
            const float m = bq((k&2) ? ((k&1)?nmH.y:nmH.x)
                                     : ((k&1)?nmL.y:nmL.x), k>>2);
            plo += splat(m) * up2(FT16a[k]);
            phi += splat(m) * up2(FT16b[k]);
        }
        *reinterpret_cast<float4*>(g_out + (size_t)g*16 + 4*l) =
            make_float4(plo.x, plo.y, phi.x, phi.y);
    }

    // ---- pred_cov rows, fused W=F@NC then out=W@F^T+Q (2-deep Q ring) ----
    float* const out_pc = g_out + (size_t)G*16 + (size_t)g*256;
    float4 qbuf[2];
    #pragma unroll
    for (int i = 0; i < 2; ++i)
        qbuf[i] = *reinterpret_cast<const float4*>(Qp + i*16 + 4*l);
    #pragma unroll
    for (int i = 0; i < 16; ++i) {
        v2f wlo = {0.f,0.f}, whi = {0.f,0.f};
        #pragma unroll
        for (int k = 0; k < 16; ++k) {
            const float f = bq((float)((i&2) ? ((i&1)?FT16b[k].y:FT16b[k].x)
                                             : ((i&1)?FT16a[k].y:FT16a[k].x)), i>>2);
            wlo += splat(f) * NClo[k];
            whi += splat(f) * NChi[k];
        }
        const float4 qv = qbuf[i & 1];
        if (i + 2 < 16)
            qbuf[i & 1] = *reinterpret_cast<const float4*>(Qp + (i+2)*16 + 4*l);
        v2f olo; olo.x=qv.x; olo.y=qv.y;
        v2f ohi; ohi.x=qv.z; ohi.y=qv.w;
        #pragma unroll
        for (int t = 0; t < 16; ++t) {
            const float wb = bq((t&2) ? ((t&1)?whi.y:whi.x)
                                      : ((t&1)?wlo.y:wlo.x), t>>2);
            olo += splat(wb) * up2(FT16a[t]);
            ohi += splat(wb) * up2(FT16b[t]);
        }
        *reinterpret_cast<float4*>(out_pc + i*16 + 4*l) =
            make_float4(olo.x, olo.y, ohi.x, ohi.y);
    }
}

extern "C" void kernel_launch(void* const* d_in, const int* in_sizes, int n_in,
                              void* d_out, int out_size, void* d_ws, size_t ws_size,
                              hipStream_t stream) {
    const float* g_in   = (const float*)d_in[0];
    const float* g_mean = (const float*)d_in[1];
    const float* g_cov  = (const float*)d_in[2];
    const float* g_H    = (const float*)d_in[3];
    const float* g_R    = (const float*)d_in[4];
    const float* g_F    = (const float*)d_in[5];
    const float* g_Q    = (const float*)d_in[6];
    float* out = (float*)d_out;
    const int G = in_sizes[2] / 256;     // cov is [G,16,16]
    kalman_kernel<<<G/64, 256, 0, stream>>>(g_in, g_mean, g_cov, g_H, g_R, g_F, g_Q, out, G);
}